// Round 23
// baseline (154.914 us; speedup 1.0000x reference)
//
#include <hip/hip_runtime.h>
#include <hip/hip_bf16.h>

#define NN 4096
#define DD 128
#define NS 75
#define TOT (NN * NN)

// k_d2: 64x128 tile, 256 threads / 4 waves (32x64 per wave)
#define NRT 64                               // 64 row-tiles of 64
#define NCT2 32                              // 32 col-tiles of 128
#define GRID_D2 1056                         // blocks with 2*tj2+1 >= ti

// sweeps/final: 64x64 tiles over upper triangle
#define SB 64
#define NBSW (NN / SB)                      // 64
#define NTILES (NBSW * (NBSW + 1) / 2)      // 2080
#define GRID_SWC (NTILES / 4)               // 520  (4 tiles/block coarse)
#define GRID_SWR (NTILES / 2)               // 1040 (2 tiles/block refine)

typedef float v2f __attribute__((ext_vector_type(2)));
typedef float f32x4 __attribute__((ext_vector_type(4)));
typedef short bf16x8 __attribute__((ext_vector_type(8)));

__device__ __forceinline__ float fexp2(float v) { return __builtin_amdgcn_exp2f(v); }

// async global->LDS, 16B per lane; lds dst is wave-uniform base (HW adds lane*16)
__device__ __forceinline__ void gload_lds16(const void* g, void* l) {
    __builtin_amdgcn_global_load_lds(
        (const __attribute__((address_space(1))) unsigned int*)g,
        (__attribute__((address_space(3))) unsigned int*)l,
        16, 0, 0);
}

// DPP lane-shift add: register-file crossing, no LDS latency.
template <int CTRL>
__device__ __forceinline__ float dpp_add(float x) {
    int y = __builtin_amdgcn_update_dpp(0, __float_as_int(x), CTRL, 0xf, 0xf, true);
    return x + __int_as_float(y);
}
__device__ __forceinline__ float wave_sum(float x) {   // result in lane 63
    x = dpp_add<0x111>(x);
    x = dpp_add<0x112>(x);
    x = dpp_add<0x114>(x);
    x = dpp_add<0x118>(x);
    x = dpp_add<0x142>(x);
    x = dpp_add<0x143>(x);
    return x;
}

// linear index -> (bi, bj) with bi <= bj, row-major over upper triangle
__device__ __forceinline__ void tri_decode(int t, int nb, int& bi, int& bj) {
    int b = 0, rem = t;
    while (rem >= nb - b) { rem -= nb - b; ++b; }
    bi = b; bj = b + rem;
}

// k_d2 block decode: ti (row-tile of 64), tj2 (col-tile of 128) with
// 2*tj2+1 >= ti; tj2min = ti>>1, count per ti = 32 - (ti>>1). Total 1056.
__device__ __forceinline__ void d2_decode(int t, int& ti, int& tj2) {
    int g = 0, rem = t;
    while (rem >= NCT2 - (g >> 1)) { rem -= NCT2 - (g >> 1); ++g; }
    ti = g; tj2 = (g >> 1) + rem;
}

// Split f32 -> bf16 hi + bf16 lo (exact residual truncated).
__device__ __forceinline__ void cvt_split(const float4& v0, const float4& v1,
                                          bf16x8& hi, bf16x8& lo) {
    float f[8] = {v0.x, v0.y, v0.z, v0.w, v1.x, v1.y, v1.z, v1.w};
#pragma unroll
    for (int j = 0; j < 8; ++j) {
        unsigned b = __float_as_uint(f[j]);
        hi[j] = (short)(b >> 16);
        float l = f[j] - __uint_as_float(b & 0xFFFF0000u);
        lo[j] = (short)(__float_as_uint(l) >> 16);
    }
}

// bf16 stash of x (hi/lo) in d2's never-read lower triangle (rows 2048..2303,
// cols < 2048). Written by k_cvt, read by k_d2, overwritten only by k_final's
// final mirror pass.
__device__ __forceinline__ const unsigned short* xrow_st(const float* d2, int i, int lo) {
    return (const unsigned short*)(d2 + (size_t)(2048 + lo * 128 + (i >> 5)) * NN + (i & 31) * 64);
}
__device__ __forceinline__ unsigned short* xrow_st_w(float* d2, int i, int lo) {
    return (unsigned short*)(d2 + (size_t)(2048 + lo * 128 + (i >> 5)) * NN + (i & 31) * 64);
}

// Coarse window logic (deterministic; recomputed per consumer block).
__device__ __forceinline__ int coarse_window(const double* KL, const double* KK) {
    double best = -1.0;
    int bk = 0;
    for (int k = 0; k < 25; ++k) {
        double loss = KL[k] / sqrt(KK[k]);
        if (loss > best) { best = loss; bk = k; }   // strict > = first max
    }
    int wv = 3 * bk - 2;
    if (wv < 0) wv = 0;
    if (wv > NS - 5) wv = NS - 5;
    return wv;
}

// ---------------- ws layout (bytes) ----------------
#define WS_DSUM 0                      // double
#define WS_NZC  8                      // unsigned long long
#define WS_KL   16                     // double[32]  (0..24 coarse, 25..29 refine)
#define WS_KK   (16 + 256)             // double[32]
#define WS_SQ   (16 + 512)             // float[NN]
#define WS_CSIG (WS_SQ + 4 * NN)       // float[NS]

__global__ void k_rowsq(const float* __restrict__ x, float* __restrict__ sq,
                        double* __restrict__ dsum, unsigned long long* __restrict__ nzc) {
    int tid = blockIdx.x * blockDim.x + threadIdx.x;
    if (tid == 0) { *dsum = 0.0; *nzc = 0ull; }
    if (tid < NN) {
        const float4* row = (const float4*)(x + (size_t)tid * DD);
        float s = 0.f;
#pragma unroll
        for (int i = 0; i < DD / 4; ++i) {
            float4 v = row[i];
            s += v.x * v.x + v.y * v.y + v.z * v.z + v.w * v.w;
        }
        sq[tid] = s;
    }
}

// One-time x -> bf16 hi/lo decomposition.
__global__ void k_cvt(const float* __restrict__ x, float* __restrict__ d2) {
    int t = blockIdx.x * blockDim.x + threadIdx.x;
    int i  = t >> 4;
    int k8 = (t & 15) * 8;
    const float* p = x + (size_t)i * DD + k8;
    float4 v0 = *(const float4*)p;
    float4 v1 = *(const float4*)(p + 4);
    bf16x8 hi, lo;
    cvt_split(v0, v1, hi, lo);
    *(bf16x8*)(xrow_st_w(d2, i, 0) + k8) = hi;
    *(bf16x8*)(xrow_st_w(d2, i, 1) + k8) = lo;
}

// d2 via split-bf16 MFMA from the stash. 64x128 tile, 256 threads / 4 waves,
// grid 1056 (~4.1 blocks/CU — fixes R22's 2.06-blocks/CU latency exposure).
// Each 64x64 half written iff its col-tile >= ti; per-wave dsum weight.
__launch_bounds__(256, 4)
__global__ void k_d2(const float* __restrict__ x, const float* __restrict__ sq,
                     float* __restrict__ d2, double* __restrict__ dsum,
                     unsigned long long* __restrict__ nzc) {
    __shared__ float st[64][132];      // 33,792 B staging
    __shared__ double red_d[4];
    __shared__ int red_n[4];

    int ti, tj2;
    d2_decode(blockIdx.x, ti, tj2);
    const int r0 = ti * 64, c0 = tj2 * 128;
    const int tid = threadIdx.x;
    const int l = tid & 63, wid = tid >> 6;
    const int wr = wid >> 1, wc = wid & 1;      // wave tile: 32 rows x 64 cols
    const int lr = l & 15;
    const int lk = (l >> 4) * 8;
    const int l4 = (l >> 4) * 4;

    const int arow = r0 + wr * 32 + lr;         // + a*16
    const int brow = c0 + wc * 64 + lr;         // + b*16
    const int tc_tile = 2 * tj2 + wc;           // this wave's 64-col tile index
    const int w_w = (tc_tile == ti) ? 1 : (tc_tile > ti ? 2 : 0);

    f32x4 acc[2][4];
#pragma unroll
    for (int a = 0; a < 2; ++a)
#pragma unroll
        for (int b = 0; b < 4; ++b) acc[a][b] = (f32x4){0.f, 0.f, 0.f, 0.f};

#pragma unroll
    for (int kc = 0; kc < 4; ++kc) {
        const int k0 = kc * 32 + lk;
        bf16x8 ah[2], al[2], bh[4], bl[4];
#pragma unroll
        for (int a = 0; a < 2; ++a) {
            ah[a] = *(const bf16x8*)(xrow_st(d2, arow + a * 16, 0) + k0);
            al[a] = *(const bf16x8*)(xrow_st(d2, arow + a * 16, 1) + k0);
        }
#pragma unroll
        for (int b = 0; b < 4; ++b) {
            bh[b] = *(const bf16x8*)(xrow_st(d2, brow + b * 16, 0) + k0);
            bl[b] = *(const bf16x8*)(xrow_st(d2, brow + b * 16, 1) + k0);
        }
#pragma unroll
        for (int a = 0; a < 2; ++a)
#pragma unroll
            for (int b = 0; b < 4; ++b) {
                acc[a][b] = __builtin_amdgcn_mfma_f32_16x16x32_bf16(ah[a], bh[b], acc[a][b], 0, 0, 0);
                acc[a][b] = __builtin_amdgcn_mfma_f32_16x16x32_bf16(ah[a], bl[b], acc[a][b], 0, 0, 0);
                acc[a][b] = __builtin_amdgcn_mfma_f32_16x16x32_bf16(al[a], bh[b], acc[a][b], 0, 0, 0);
            }
    }

    // d2 = max(sq_r + sq_c - 2G, 0); dist-sum/nnz (per-wave weight w_w).
    float myd = 0.f;
    int myn = 0;
#pragma unroll
    for (int a = 0; a < 2; ++a) {
        const int grb = r0 + wr * 32 + a * 16 + l4;
        float4 sqr = *(const float4*)(sq + grb);
        float sr[4] = {sqr.x, sqr.y, sqr.z, sqr.w};
#pragma unroll
        for (int b = 0; b < 4; ++b) {
            const float sc = sq[c0 + wc * 64 + b * 16 + lr];
#pragma unroll
            for (int v = 0; v < 4; ++v) {
                float d = fmaxf(sr[v] + sc - 2.f * acc[a][b][v], 0.f);
                acc[a][b][v] = d;
                if (d > 0.f) { myd += sqrtf(d); ++myn; }
            }
        }
    }
    float sd = wave_sum(myd);
    float sn = wave_sum((float)myn);
    if (l == 63) { red_d[wid] = (double)sd * w_w; red_n[wid] = (int)sn * w_w; }

    // stage (each wave its 32x64 quadrant), then cooperative coalesced write
    const int srow = wr * 32 + l4;
#pragma unroll
    for (int a = 0; a < 2; ++a)
#pragma unroll
        for (int b = 0; b < 4; ++b)
#pragma unroll
            for (int v = 0; v < 4; ++v)
                st[srow + a * 16 + v][wc * 64 + b * 16 + lr] = acc[a][b][v];
    __syncthreads();

    const bool lhalf = (2 * tj2 >= ti);
    if (lhalf) {
#pragma unroll
        for (int q = 0; q < 8; ++q) {
            const int rr = q * 8 + (tid >> 5);
            const int cc = (tid & 31) * 4;
            *(f32x4*)(d2 + (size_t)(r0 + rr) * NN + c0 + cc) = *(const f32x4*)&st[rr][cc];
        }
    } else {
#pragma unroll
        for (int q = 0; q < 4; ++q) {
            const int rr = q * 16 + (tid >> 4);
            const int cc = 64 + (tid & 15) * 4;
            *(f32x4*)(d2 + (size_t)(r0 + rr) * NN + c0 + cc) = *(const f32x4*)&st[rr][cc];
        }
    }

    if (tid == 0) {
        double td = red_d[0] + red_d[1] + red_d[2] + red_d[3];
        int tn = red_n[0] + red_n[1] + red_n[2] + red_n[3];
        atomicAdd(dsum, td);
        atomicAdd(nzc, (unsigned long long)tn);
    }
}

__global__ void k_sigmas(const double* __restrict__ dsum, const unsigned long long* __restrict__ nzc,
                         float* __restrict__ csig, double* __restrict__ KL, double* __restrict__ KK) {
    int t = threadIdx.x;
    float mean = (float)(*dsum / (double)(*nzc));
    float lo = 0.1f * mean;
    float hi = 10.0f * mean;
    float step = (hi - lo) / (float)NS;
    if (t < NS) {
        float s = lo + step * (float)t;
        csig[t] = (float)(1.4426950408889634 / ((double)s * (double)s));
    }
    if (t < 32) { KL[t] = 0.0; KK[t] = 0.0; }
}

// One sigma-phase over register-resident data. ADD=false stores w*v,
// ADD=true accumulates.
template <bool ADD, int CH, int S0, int STRIDE, int NSLOT>
__device__ __forceinline__ void sweep_phase(const v2f* nd, const v2f* ll,
                                            const float* __restrict__ csig, int off,
                                            double part[4][2 * NSLOT],
                                            int wave, int lane, float w) {
    float c[CH];
#pragma unroll
    for (int s = 0; s < CH; ++s)   // force SGPR residency
        c[s] = __int_as_float(__builtin_amdgcn_readfirstlane(
                   __float_as_int(csig[off + STRIDE * (S0 + s)])));
    v2f akl[CH], akk[CH];
#pragma unroll
    for (int s = 0; s < CH; ++s) { akl[s] = (v2f){0.f, 0.f}; akk[s] = (v2f){0.f, 0.f}; }

#pragma unroll
    for (int e = 0; e < 8; ++e) {
        v2f ndv = nd[e], L = ll[e];
#pragma unroll
        for (int s = 0; s < CH; ++s) {
            v2f arg = ndv * c[s];                               // v_pk_mul_f32
            v2f K = {fexp2(arg.x), fexp2(arg.y)};               // 2x v_exp_f32
            akl[s] = __builtin_elementwise_fma(K, L, akl[s]);   // v_pk_fma_f32
            akk[s] = __builtin_elementwise_fma(K, K, akk[s]);
        }
    }

#pragma unroll
    for (int s = 0; s < CH; ++s) {
        float v1 = wave_sum(akl[s].x + akl[s].y);
        float v2 = wave_sum(akk[s].x + akk[s].y);
        if (lane == 63) {
            if (ADD) {
                part[wave][S0 + s]         += (double)(v1 * w);
                part[wave][NSLOT + S0 + s] += (double)(v2 * w);
            } else {
                part[wave][S0 + s]         = (double)(v1 * w);
                part[wave][NSLOT + S0 + s] = (double)(v2 * w);
            }
        }
    }
}

// Direct load: 16 elems/thread into registers.
__device__ __forceinline__ void sweep_load_direct(const float* __restrict__ d2,
                                                  const float* __restrict__ lk,
                                                  int r0, int c0, v2f* nd, v2f* ll) {
    const int rr = threadIdx.x >> 4;
    const int c4 = (threadIdx.x & 15) * 4;
#pragma unroll
    for (int it = 0; it < 4; ++it) {
        size_t off = (size_t)(r0 + rr + 16 * it) * NN + c0 + c4;
        float4 dv = *(const float4*)(d2 + off);
        float4 lv = *(const float4*)(lk + off);
        nd[it * 2 + 0] = (v2f){-dv.x, -dv.y};
        nd[it * 2 + 1] = (v2f){-dv.z, -dv.w};
        ll[it * 2 + 0] = (v2f){lv.x, lv.y};
        ll[it * 2 + 1] = (v2f){lv.z, lv.w};
    }
}

// Prefetch via global_load_lds into this wave's 8KB LDS slot.
__device__ __forceinline__ void sweep_prefetch(const float* __restrict__ d2,
                                               const float* __restrict__ lk,
                                               int r0, int c0, char* wbuf) {
    const int l = threadIdx.x & 63;
    const int wave4 = (threadIdx.x >> 6) * 4;
    const int rr = wave4 + (l >> 4);
    const int c4 = (l & 15) * 4;
#pragma unroll
    for (int q = 0; q < 4; ++q) {
        size_t off = (size_t)(r0 + rr + 16 * q) * NN + c0 + c4;
        gload_lds16(d2 + off, wbuf + q * 1024);
        gload_lds16(lk + off, wbuf + (4 + q) * 1024);
    }
}

__device__ __forceinline__ void sweep_unpack(const char* wbuf, v2f* nd, v2f* ll) {
    const int l = threadIdx.x & 63;
#pragma unroll
    for (int q = 0; q < 4; ++q) {
        f32x4 dv = *(const f32x4*)(wbuf + q * 1024 + l * 16);
        f32x4 lv = *(const f32x4*)(wbuf + (4 + q) * 1024 + l * 16);
        nd[q * 2 + 0] = (v2f){-dv[0], -dv[1]};
        nd[q * 2 + 1] = (v2f){-dv[2], -dv[3]};
        ll[q * 2 + 0] = (v2f){lv[0], lv[1]};
        ll[q * 2 + 1] = (v2f){lv[2], lv[3]};
    }
}

// Coarse: 4 tiles/block, rolling single-slot LDS prefetch (t_{i+1}'s HBM/L3
// latency hides under t_i's 25-sigma compute; per-block fixed costs
// amortized 2x vs R22's 2-tile).
__launch_bounds__(256, 3)
__global__ void k_sweep_coarse(const float* __restrict__ d2, const float* __restrict__ lk,
                               const float* __restrict__ csig, double* __restrict__ KL,
                               double* __restrict__ KK) {
    __shared__ char pbuf[4][8192];
    __shared__ double part[4][50];
    const int lane = threadIdx.x & 63, wave = threadIdx.x >> 6;

    int bi[4], bj[4];
    float w[4];
#pragma unroll
    for (int i = 0; i < 4; ++i) {
        tri_decode(blockIdx.x * 4 + i, NBSW, bi[i], bj[i]);
        w[i] = (bi[i] == bj[i]) ? 1.f : 2.f;
    }

    sweep_prefetch(d2, lk, bi[1] * SB, bj[1] * SB, &pbuf[wave][0]);
    v2f nd[8], ll[8];
    sweep_load_direct(d2, lk, bi[0] * SB, bj[0] * SB, nd, ll);

    sweep_phase<false, 13, 0, 3, 25>(nd, ll, csig, 0, part, wave, lane, w[0]);
    sweep_phase<false, 12, 13, 3, 25>(nd, ll, csig, 0, part, wave, lane, w[0]);

    // t1: wait, unpack, reissue slot for t2, compute
    asm volatile("s_waitcnt vmcnt(0)" ::: "memory");
    sweep_unpack(&pbuf[wave][0], nd, ll);
    asm volatile("s_waitcnt lgkmcnt(0)" ::: "memory");
    __builtin_amdgcn_sched_barrier(0);
    sweep_prefetch(d2, lk, bi[2] * SB, bj[2] * SB, &pbuf[wave][0]);
    sweep_phase<true, 13, 0, 3, 25>(nd, ll, csig, 0, part, wave, lane, w[1]);
    sweep_phase<true, 12, 13, 3, 25>(nd, ll, csig, 0, part, wave, lane, w[1]);

    // t2
    asm volatile("s_waitcnt vmcnt(0)" ::: "memory");
    sweep_unpack(&pbuf[wave][0], nd, ll);
    asm volatile("s_waitcnt lgkmcnt(0)" ::: "memory");
    __builtin_amdgcn_sched_barrier(0);
    sweep_prefetch(d2, lk, bi[3] * SB, bj[3] * SB, &pbuf[wave][0]);
    sweep_phase<true, 13, 0, 3, 25>(nd, ll, csig, 0, part, wave, lane, w[2]);
    sweep_phase<true, 12, 13, 3, 25>(nd, ll, csig, 0, part, wave, lane, w[2]);

    // t3
    asm volatile("s_waitcnt vmcnt(0)" ::: "memory");
    sweep_unpack(&pbuf[wave][0], nd, ll);
    sweep_phase<true, 13, 0, 3, 25>(nd, ll, csig, 0, part, wave, lane, w[3]);
    sweep_phase<true, 12, 13, 3, 25>(nd, ll, csig, 0, part, wave, lane, w[3]);

    __syncthreads();
    const int t = threadIdx.x;
    if (t < 50) {
        double v = part[0][t] + part[1][t] + part[2][t] + part[3][t];
        if (t < 25) atomicAdd(&KL[t], v);
        else        atomicAdd(&KK[t - 25], v);
    }
}

// Refine: 2-tile structure (proven), 5 stride-1 sigmas at the coarse window.
__launch_bounds__(256, 3)
__global__ void k_sweep_refine(const float* __restrict__ d2, const float* __restrict__ lk,
                               const float* __restrict__ csig, double* __restrict__ KL,
                               double* __restrict__ KK) {
    __shared__ char pbuf[4][8192];
    __shared__ double part[4][10];
    __shared__ int w0_sh;
    if (threadIdx.x == 0) w0_sh = coarse_window(KL, KK);
    const int lane = threadIdx.x & 63, wave = threadIdx.x >> 6;

    int t0 = blockIdx.x * 2, t1 = t0 + 1;
    int bi0, bj0, bi1, bj1;
    tri_decode(t0, NBSW, bi0, bj0);
    tri_decode(t1, NBSW, bi1, bj1);
    const float wt0 = (bi0 == bj0) ? 1.f : 2.f;
    const float wt1 = (bi1 == bj1) ? 1.f : 2.f;

    sweep_prefetch(d2, lk, bi1 * SB, bj1 * SB, &pbuf[wave][0]);
    v2f nd[8], ll[8];
    sweep_load_direct(d2, lk, bi0 * SB, bj0 * SB, nd, ll);
    __syncthreads();                 // w0_sh visible
    const int s0 = w0_sh;

    sweep_phase<false, 5, 0, 1, 5>(nd, ll, csig, s0, part, wave, lane, wt0);

    asm volatile("s_waitcnt vmcnt(0)" ::: "memory");
    sweep_unpack(&pbuf[wave][0], nd, ll);

    sweep_phase<true, 5, 0, 1, 5>(nd, ll, csig, s0, part, wave, lane, wt1);

    __syncthreads();
    const int t = threadIdx.x;
    if (t < 10) {
        double v = part[0][t] + part[1][t] + part[2][t] + part[3][t];
        if (t < 5) atomicAdd(&KL[25 + t], v);
        else       atomicAdd(&KK[25 + t - 5], v);
    }
}

// Final: tile-based over the upper triangle (grid 2080). Reads the upper
// d2 tile, A = exp2(-d2*c)/n, direct write + LDS-transposed mirror
// (also overwrites the bf16 stash — last consumer, safe).
__global__ void k_final(float* __restrict__ d2, const double* __restrict__ KL,
                        const double* __restrict__ KK, const float* __restrict__ csig) {
    __shared__ float st[64][68];
    __shared__ float cc_sh;
    if (threadIdx.x == 0) {
        int wv = coarse_window(KL, KK);
        double best = -1.0;
        int bk = 0;
        for (int k = 0; k < 5; ++k) {
            double loss = KL[25 + k] / sqrt(KK[25 + k]);
            if (loss > best) { best = loss; bk = k; }
        }
        cc_sh = csig[wv + bk];
    }
    __syncthreads();
    const float cc = cc_sh;
    const float inv_n = 1.0f / (float)NN;

    int ti, tj;
    tri_decode(blockIdx.x, NBSW, ti, tj);
    const int r0 = ti * SB, c0 = tj * SB;
    const int tid = threadIdx.x;

#pragma unroll
    for (int q = 0; q < 4; ++q) {
        const int rr = q * 16 + (tid >> 4);
        const int cc4 = (tid & 15) * 4;
        float* p = d2 + (size_t)(r0 + rr) * NN + c0 + cc4;
        f32x4 v = *(const f32x4*)p;
        v[0] = fexp2(-v[0] * cc) * inv_n;
        v[1] = fexp2(-v[1] * cc) * inv_n;
        v[2] = fexp2(-v[2] * cc) * inv_n;
        v[3] = fexp2(-v[3] * cc) * inv_n;
        *(f32x4*)p = v;                              // direct (in-place)
        *(f32x4*)&st[rr][cc4] = v;                   // stage for mirror
    }

    if (ti != tj) {
        __syncthreads();
#pragma unroll
        for (int q = 0; q < 4; ++q) {
            const int tc = q * 16 + (tid >> 4);      // tile col = out row
            const int rb = (tid & 15) * 4;           // tile row base = out col base
            f32x4 vv = {st[rb + 0][tc], st[rb + 1][tc], st[rb + 2][tc], st[rb + 3][tc]};
            *(f32x4*)(d2 + (size_t)(c0 + tc) * NN + r0 + rb) = vv;
        }
    }
}

extern "C" void kernel_launch(void* const* d_in, const int* in_sizes, int n_in,
                              void* d_out, int out_size, void* d_ws, size_t ws_size,
                              hipStream_t stream) {
    const float* x  = (const float*)d_in[0];
    const float* lk = (const float*)d_in[1];
    float* out = (float*)d_out;   // d2 buffer + bf16 stash, transformed in place
    char* ws = (char*)d_ws;

    double* dsum = (double*)(ws + WS_DSUM);
    unsigned long long* nzc = (unsigned long long*)(ws + WS_NZC);
    double* KL = (double*)(ws + WS_KL);
    double* KK = (double*)(ws + WS_KK);
    float* sqv  = (float*)(ws + WS_SQ);
    float* csig = (float*)(ws + WS_CSIG);

    hipLaunchKernelGGL(k_rowsq, dim3(NN / 256), dim3(256), 0, stream, x, sqv, dsum, nzc);
    hipLaunchKernelGGL(k_cvt, dim3(256), dim3(256), 0, stream, x, out);
    hipLaunchKernelGGL(k_d2, dim3(GRID_D2), dim3(256), 0, stream, x, sqv, out, dsum, nzc);
    hipLaunchKernelGGL(k_sigmas, dim3(1), dim3(128), 0, stream, dsum, nzc, csig, KL, KK);
    hipLaunchKernelGGL(k_sweep_coarse, dim3(GRID_SWC), dim3(256), 0, stream, out, lk, csig, KL, KK);
    hipLaunchKernelGGL(k_sweep_refine, dim3(GRID_SWR), dim3(256), 0, stream, out, lk, csig, KL, KK);
    hipLaunchKernelGGL(k_final, dim3(NTILES), dim3(256), 0, stream, out, KL, KK, csig);
}

// Round 24
// 147.831 us; speedup vs baseline: 1.0479x; 1.0479x over previous
//
#include <hip/hip_runtime.h>
#include <hip/hip_bf16.h>

#define NN 4096
#define DD 128
#define NS 75
#define TOT (NN * NN)

// k_d2: 128x128 tile, 512 threads / 8 waves (32x64 per wave), upper-tri grid
#define BT 128
#define NBD2 (NN / BT)                      // 32
#define GRID_D2 (NBD2 * (NBD2 + 1) / 2)     // 528

// sweeps/final: 64x64 tiles over upper triangle
#define SB 64
#define NBSW (NN / SB)                      // 64
#define NTILES (NBSW * (NBSW + 1) / 2)      // 2080
#define GRID_SW (NTILES / 2)                // 1040  (2 tiles/block in sweeps)

typedef float v2f __attribute__((ext_vector_type(2)));
typedef float f32x4 __attribute__((ext_vector_type(4)));
typedef short bf16x8 __attribute__((ext_vector_type(8)));

__device__ __forceinline__ float fexp2(float v) { return __builtin_amdgcn_exp2f(v); }

// async global->LDS, 16B per lane; lds dst is wave-uniform base (HW adds lane*16)
__device__ __forceinline__ void gload_lds16(const void* g, void* l) {
    __builtin_amdgcn_global_load_lds(
        (const __attribute__((address_space(1))) unsigned int*)g,
        (__attribute__((address_space(3))) unsigned int*)l,
        16, 0, 0);
}

// DPP lane-shift add: register-file crossing, no LDS latency.
template <int CTRL>
__device__ __forceinline__ float dpp_add(float x) {
    int y = __builtin_amdgcn_update_dpp(0, __float_as_int(x), CTRL, 0xf, 0xf, true);
    return x + __int_as_float(y);
}
__device__ __forceinline__ float wave_sum(float x) {   // result in lane 63
    x = dpp_add<0x111>(x);
    x = dpp_add<0x112>(x);
    x = dpp_add<0x114>(x);
    x = dpp_add<0x118>(x);
    x = dpp_add<0x142>(x);
    x = dpp_add<0x143>(x);
    return x;
}

// linear index -> (bi, bj) with bi <= bj, row-major over upper triangle
__device__ __forceinline__ void tri_decode(int t, int nb, int& bi, int& bj) {
    int b = 0, rem = t;
    while (rem >= nb - b) { rem -= nb - b; ++b; }
    bi = b; bj = b + rem;
}

// Split f32 -> bf16 hi + bf16 lo (exact residual truncated).
__device__ __forceinline__ void cvt_split(const float4& v0, const float4& v1,
                                          bf16x8& hi, bf16x8& lo) {
    float f[8] = {v0.x, v0.y, v0.z, v0.w, v1.x, v1.y, v1.z, v1.w};
#pragma unroll
    for (int j = 0; j < 8; ++j) {
        unsigned b = __float_as_uint(f[j]);
        hi[j] = (short)(b >> 16);
        float l = f[j] - __uint_as_float(b & 0xFFFF0000u);
        lo[j] = (short)(__float_as_uint(l) >> 16);
    }
}

// bf16 stash of x (hi/lo) in d2's never-read lower triangle (rows 2048..2303,
// cols < 2048). Written by k_cvt, read by k_d2, overwritten only by k_final's
// final mirror pass (last consumer — safe).
__device__ __forceinline__ const unsigned short* xrow_st(const float* d2, int i, int lo) {
    return (const unsigned short*)(d2 + (size_t)(2048 + lo * 128 + (i >> 5)) * NN + (i & 31) * 64);
}
__device__ __forceinline__ unsigned short* xrow_st_w(float* d2, int i, int lo) {
    return (unsigned short*)(d2 + (size_t)(2048 + lo * 128 + (i >> 5)) * NN + (i & 31) * 64);
}

// Sigma constants computed per consumer block (k_sigmas launch eliminated).
// Bitwise-identical sequence to the old k_sigmas: f32 mean/lo/step, f64 /s^2.
__device__ __forceinline__ void sig_base(const double* dsum, const unsigned long long* nzc,
                                         float& lo, float& step) {
    float mean = (float)(*dsum / (double)(*nzc));
    lo = 0.1f * mean;
    float hi = 10.0f * mean;
    step = (hi - lo) / (float)NS;
}
__device__ __forceinline__ float sig_c(float lo, float step, int idx) {
    float s = lo + step * (float)idx;
    return (float)(1.4426950408889634 / ((double)s * (double)s));
}

// Coarse window logic (deterministic; recomputed per consumer block).
__device__ __forceinline__ int coarse_window(const double* KL, const double* KK) {
    double best = -1.0;
    int bk = 0;
    for (int k = 0; k < 25; ++k) {
        double loss = KL[k] / sqrt(KK[k]);
        if (loss > best) { best = loss; bk = k; }   // strict > = first max
    }
    int wv = 3 * bk - 2;
    if (wv < 0) wv = 0;
    if (wv > NS - 5) wv = NS - 5;
    return wv;
}

// ---------------- ws layout (bytes) ----------------
#define WS_DSUM 0                      // double
#define WS_NZC  8                      // unsigned long long
#define WS_KL   16                     // double[32]  (0..24 coarse, 25..29 refine)
#define WS_KK   (16 + 256)             // double[32]
#define WS_SQ   (16 + 512)             // float[NN]

__global__ void k_rowsq(const float* __restrict__ x, float* __restrict__ sq,
                        double* __restrict__ dsum, unsigned long long* __restrict__ nzc,
                        double* __restrict__ KL, double* __restrict__ KK) {
    int tid = blockIdx.x * blockDim.x + threadIdx.x;
    if (tid == 0) { *dsum = 0.0; *nzc = 0ull; }
    if (blockIdx.x == 0 && threadIdx.x < 32) { KL[threadIdx.x] = 0.0; KK[threadIdx.x] = 0.0; }
    if (tid < NN) {
        const float4* row = (const float4*)(x + (size_t)tid * DD);
        float s = 0.f;
#pragma unroll
        for (int i = 0; i < DD / 4; ++i) {
            float4 v = row[i];
            s += v.x * v.x + v.y * v.y + v.z * v.z + v.w * v.w;
        }
        sq[tid] = s;
    }
}

// One-time x -> bf16 hi/lo decomposition.
__global__ void k_cvt(const float* __restrict__ x, float* __restrict__ d2) {
    int t = blockIdx.x * blockDim.x + threadIdx.x;
    int i  = t >> 4;
    int k8 = (t & 15) * 8;
    const float* p = x + (size_t)i * DD + k8;
    float4 v0 = *(const float4*)p;
    float4 v1 = *(const float4*)(p + 4);
    bf16x8 hi, lo;
    cvt_split(v0, v1, hi, lo);
    *(bf16x8*)(xrow_st_w(d2, i, 0) + k8) = hi;
    *(bf16x8*)(xrow_st_w(d2, i, 1) + k8) = lo;
}

// d2 via split-bf16 MFMA from the stash. 128x128 tile, 512 threads / 8 waves
// (R22 config — best measured). Writes UPPER TILE ONLY; k_final mirrors.
__launch_bounds__(512, 2)
__global__ void k_d2(const float* __restrict__ x, const float* __restrict__ sq,
                     float* __restrict__ d2, double* __restrict__ dsum,
                     unsigned long long* __restrict__ nzc) {
    __shared__ float st[64][132];      // 33,792 B: 64-row staging pass, pad 4
    __shared__ double red_d[8];
    __shared__ int red_n[8];

    int bi, bj;
    tri_decode(blockIdx.x, NBD2, bi, bj);
    const int r0 = bi * BT, c0 = bj * BT;
    const int tid = threadIdx.x;
    const int l = tid & 63, wid = tid >> 6;
    const int wr = wid >> 1, wc = wid & 1;
    const int lr = l & 15;
    const int lk = (l >> 4) * 8;
    const int l4 = (l >> 4) * 4;

    const int arow = r0 + wr * 32 + lr;     // + a*16
    const int brow = c0 + wc * 64 + lr;     // + b*16

    f32x4 acc[2][4];
#pragma unroll
    for (int a = 0; a < 2; ++a)
#pragma unroll
        for (int b = 0; b < 4; ++b) acc[a][b] = (f32x4){0.f, 0.f, 0.f, 0.f};

#pragma unroll
    for (int kc = 0; kc < 4; ++kc) {
        const int k0 = kc * 32 + lk;
        bf16x8 ah[2], al[2], bh[4], bl[4];
#pragma unroll
        for (int a = 0; a < 2; ++a) {
            ah[a] = *(const bf16x8*)(xrow_st(d2, arow + a * 16, 0) + k0);
            al[a] = *(const bf16x8*)(xrow_st(d2, arow + a * 16, 1) + k0);
        }
#pragma unroll
        for (int b = 0; b < 4; ++b) {
            bh[b] = *(const bf16x8*)(xrow_st(d2, brow + b * 16, 0) + k0);
            bl[b] = *(const bf16x8*)(xrow_st(d2, brow + b * 16, 1) + k0);
        }
#pragma unroll
        for (int a = 0; a < 2; ++a)
#pragma unroll
            for (int b = 0; b < 4; ++b) {
                acc[a][b] = __builtin_amdgcn_mfma_f32_16x16x32_bf16(ah[a], bh[b], acc[a][b], 0, 0, 0);
                acc[a][b] = __builtin_amdgcn_mfma_f32_16x16x32_bf16(ah[a], bl[b], acc[a][b], 0, 0, 0);
                acc[a][b] = __builtin_amdgcn_mfma_f32_16x16x32_bf16(al[a], bh[b], acc[a][b], 0, 0, 0);
            }
    }

    // d2 = max(sq_r + sq_c - 2G, 0); dist-sum/nnz reduction.
    float myd = 0.f;
    int myn = 0;
#pragma unroll
    for (int a = 0; a < 2; ++a) {
        const int grb = r0 + wr * 32 + a * 16 + l4;
        float4 sqr = *(const float4*)(sq + grb);
        float sr[4] = {sqr.x, sqr.y, sqr.z, sqr.w};
#pragma unroll
        for (int b = 0; b < 4; ++b) {
            const float sc = sq[c0 + wc * 64 + b * 16 + lr];
#pragma unroll
            for (int v = 0; v < 4; ++v) {
                float d = fmaxf(sr[v] + sc - 2.f * acc[a][b][v], 0.f);
                acc[a][b][v] = d;
                if (d > 0.f) { myd += sqrtf(d); ++myn; }
            }
        }
    }
    const int w = (bi == bj) ? 1 : 2;
    float sd = wave_sum(myd);
    float sn = wave_sum((float)myn);
    if (l == 63) { red_d[wid] = (double)sd; red_n[wid] = (int)sn; }

    // Two 64-row staging passes; waves wr in {2p, 2p+1} stage, all write.
#pragma unroll
    for (int p = 0; p < 2; ++p) {
        __syncthreads();
        if ((wr >> 1) == p) {
            const int lrow = (wr & 1) * 32 + l4;    // 0..63 within pass
#pragma unroll
            for (int a = 0; a < 2; ++a)
#pragma unroll
                for (int b = 0; b < 4; ++b)
#pragma unroll
                    for (int v = 0; v < 4; ++v)
                        st[lrow + (a == 1 ? 16 : 0) + v][wc * 64 + b * 16 + lr] = acc[a][b][v];
        }
        __syncthreads();
        // cooperative coalesced write: 64 rows x 128 cols, 512B runs
#pragma unroll
        for (int q = 0; q < 4; ++q) {
            const int rr = q * 16 + (tid >> 5);     // 0..63
            const int cc = (tid & 31) * 4;          // 0..124
            *(f32x4*)(d2 + (size_t)(r0 + p * 64 + rr) * NN + c0 + cc) =
                *(const f32x4*)&st[rr][cc];
        }
    }

    if (tid == 0) {
        double td = 0.0;
        int tn = 0;
#pragma unroll
        for (int q = 0; q < 8; ++q) { td += red_d[q]; tn += red_n[q]; }
        atomicAdd(dsum, td * (double)w);
        atomicAdd(nzc, (unsigned long long)(tn * w));
    }
}

// One sigma-phase over register-resident data. ADD=false stores w*v,
// ADD=true accumulates (second tile). Sigma consts computed from lo/step.
template <bool ADD, int CH, int S0, int STRIDE, int NSLOT>
__device__ __forceinline__ void sweep_phase(const v2f* nd, const v2f* ll,
                                            float lo, float step, int off,
                                            double part[4][2 * NSLOT],
                                            int wave, int lane, float w) {
    float c[CH];
#pragma unroll
    for (int s = 0; s < CH; ++s)   // force SGPR residency
        c[s] = __int_as_float(__builtin_amdgcn_readfirstlane(
                   __float_as_int(sig_c(lo, step, off + STRIDE * (S0 + s)))));
    v2f akl[CH], akk[CH];
#pragma unroll
    for (int s = 0; s < CH; ++s) { akl[s] = (v2f){0.f, 0.f}; akk[s] = (v2f){0.f, 0.f}; }

#pragma unroll
    for (int e = 0; e < 8; ++e) {
        v2f ndv = nd[e], L = ll[e];
#pragma unroll
        for (int s = 0; s < CH; ++s) {
            v2f arg = ndv * c[s];                               // v_pk_mul_f32
            v2f K = {fexp2(arg.x), fexp2(arg.y)};               // 2x v_exp_f32
            akl[s] = __builtin_elementwise_fma(K, L, akl[s]);   // v_pk_fma_f32
            akk[s] = __builtin_elementwise_fma(K, K, akk[s]);
        }
    }

#pragma unroll
    for (int s = 0; s < CH; ++s) {
        float v1 = wave_sum(akl[s].x + akl[s].y);
        float v2 = wave_sum(akk[s].x + akk[s].y);
        if (lane == 63) {
            if (ADD) {
                part[wave][S0 + s]         += (double)(v1 * w);
                part[wave][NSLOT + S0 + s] += (double)(v2 * w);
            } else {
                part[wave][S0 + s]         = (double)(v1 * w);
                part[wave][NSLOT + S0 + s] = (double)(v2 * w);
            }
        }
    }
}

// Direct (tile0) load: 16 elems/thread into registers.
__device__ __forceinline__ void sweep_load_direct(const float* __restrict__ d2,
                                                  const float* __restrict__ lk,
                                                  int r0, int c0, v2f* nd, v2f* ll) {
    const int rr = threadIdx.x >> 4;
    const int c4 = (threadIdx.x & 15) * 4;
#pragma unroll
    for (int it = 0; it < 4; ++it) {
        size_t off = (size_t)(r0 + rr + 16 * it) * NN + c0 + c4;
        float4 dv = *(const float4*)(d2 + off);
        float4 lv = *(const float4*)(lk + off);
        nd[it * 2 + 0] = (v2f){-dv.x, -dv.y};
        nd[it * 2 + 1] = (v2f){-dv.z, -dv.w};
        ll[it * 2 + 0] = (v2f){lv.x, lv.y};
        ll[it * 2 + 1] = (v2f){lv.z, lv.w};
    }
}

// Prefetch (tile1) via global_load_lds into this wave's 8KB LDS slot.
__device__ __forceinline__ void sweep_prefetch(const float* __restrict__ d2,
                                               const float* __restrict__ lk,
                                               int r0, int c0, char* wbuf) {
    const int l = threadIdx.x & 63;
    const int wave4 = (threadIdx.x >> 6) * 4;
    const int rr = wave4 + (l >> 4);
    const int c4 = (l & 15) * 4;
#pragma unroll
    for (int q = 0; q < 4; ++q) {
        size_t off = (size_t)(r0 + rr + 16 * q) * NN + c0 + c4;
        gload_lds16(d2 + off, wbuf + q * 1024);
        gload_lds16(lk + off, wbuf + (4 + q) * 1024);
    }
}

__device__ __forceinline__ void sweep_unpack(const char* wbuf, v2f* nd, v2f* ll) {
    const int l = threadIdx.x & 63;
#pragma unroll
    for (int q = 0; q < 4; ++q) {
        f32x4 dv = *(const f32x4*)(wbuf + q * 1024 + l * 16);
        f32x4 lv = *(const f32x4*)(wbuf + (4 + q) * 1024 + l * 16);
        nd[q * 2 + 0] = (v2f){-dv[0], -dv[1]};
        nd[q * 2 + 1] = (v2f){-dv[2], -dv[3]};
        ll[q * 2 + 0] = (v2f){lv[0], lv[1]};
        ll[q * 2 + 1] = (v2f){lv[2], lv[3]};
    }
}

// Coarse: 2 tiles/block (R22 config); tile1 async-prefetched under tile0's
// 25-sigma compute. Sigma consts computed per block (no k_sigmas launch).
__launch_bounds__(256, 3)
__global__ void k_sweep_coarse(const float* __restrict__ d2, const float* __restrict__ lk,
                               const double* __restrict__ dsum,
                               const unsigned long long* __restrict__ nzc,
                               double* __restrict__ KL, double* __restrict__ KK) {
    __shared__ char pbuf[4][8192];
    __shared__ double part[4][50];
    const int lane = threadIdx.x & 63, wave = threadIdx.x >> 6;

    int t0 = blockIdx.x * 2, t1 = t0 + 1;
    int bi0, bj0, bi1, bj1;
    tri_decode(t0, NBSW, bi0, bj0);
    tri_decode(t1, NBSW, bi1, bj1);
    const float w0 = (bi0 == bj0) ? 1.f : 2.f;
    const float w1 = (bi1 == bj1) ? 1.f : 2.f;

    sweep_prefetch(d2, lk, bi1 * SB, bj1 * SB, &pbuf[wave][0]);
    float lo, stp;
    sig_base(dsum, nzc, lo, stp);
    v2f nd[8], ll[8];
    sweep_load_direct(d2, lk, bi0 * SB, bj0 * SB, nd, ll);

    sweep_phase<false, 13, 0, 3, 25>(nd, ll, lo, stp, 0, part, wave, lane, w0);
    sweep_phase<false, 12, 13, 3, 25>(nd, ll, lo, stp, 0, part, wave, lane, w0);

    asm volatile("s_waitcnt vmcnt(0)" ::: "memory");
    sweep_unpack(&pbuf[wave][0], nd, ll);

    sweep_phase<true, 13, 0, 3, 25>(nd, ll, lo, stp, 0, part, wave, lane, w1);
    sweep_phase<true, 12, 13, 3, 25>(nd, ll, lo, stp, 0, part, wave, lane, w1);

    __syncthreads();
    const int t = threadIdx.x;
    if (t < 50) {
        double v = part[0][t] + part[1][t] + part[2][t] + part[3][t];
        if (t < 25) atomicAdd(&KL[t], v);
        else        atomicAdd(&KK[t - 25], v);
    }
}

// Refine: same 2-tile structure, 5 stride-1 sigmas at the coarse window.
__launch_bounds__(256, 3)
__global__ void k_sweep_refine(const float* __restrict__ d2, const float* __restrict__ lk,
                               const double* __restrict__ dsum,
                               const unsigned long long* __restrict__ nzc,
                               double* __restrict__ KL, double* __restrict__ KK) {
    __shared__ char pbuf[4][8192];
    __shared__ double part[4][10];
    __shared__ int w0_sh;
    if (threadIdx.x == 0) w0_sh = coarse_window(KL, KK);
    const int lane = threadIdx.x & 63, wave = threadIdx.x >> 6;

    int t0 = blockIdx.x * 2, t1 = t0 + 1;
    int bi0, bj0, bi1, bj1;
    tri_decode(t0, NBSW, bi0, bj0);
    tri_decode(t1, NBSW, bi1, bj1);
    const float wt0 = (bi0 == bj0) ? 1.f : 2.f;
    const float wt1 = (bi1 == bj1) ? 1.f : 2.f;

    sweep_prefetch(d2, lk, bi1 * SB, bj1 * SB, &pbuf[wave][0]);
    float lo, stp;
    sig_base(dsum, nzc, lo, stp);
    v2f nd[8], ll[8];
    sweep_load_direct(d2, lk, bi0 * SB, bj0 * SB, nd, ll);
    __syncthreads();                 // w0_sh visible
    const int s0 = w0_sh;

    sweep_phase<false, 5, 0, 1, 5>(nd, ll, lo, stp, s0, part, wave, lane, wt0);

    asm volatile("s_waitcnt vmcnt(0)" ::: "memory");
    sweep_unpack(&pbuf[wave][0], nd, ll);

    sweep_phase<true, 5, 0, 1, 5>(nd, ll, lo, stp, s0, part, wave, lane, wt1);

    __syncthreads();
    const int t = threadIdx.x;
    if (t < 10) {
        double v = part[0][t] + part[1][t] + part[2][t] + part[3][t];
        if (t < 5) atomicAdd(&KL[25 + t], v);
        else       atomicAdd(&KK[25 + t - 5], v);
    }
}

// Final: tile-based over the upper triangle (grid 2080). Reads the upper
// d2 tile, A = exp2(-d2*c)/n, direct write + LDS-transposed mirror
// (also overwrites the bf16 stash — last consumer, safe).
__global__ void k_final(float* __restrict__ d2, const double* __restrict__ dsum,
                        const unsigned long long* __restrict__ nzc,
                        const double* __restrict__ KL, const double* __restrict__ KK) {
    __shared__ float st[64][68];
    __shared__ float cc_sh;
    if (threadIdx.x == 0) {
        int wv = coarse_window(KL, KK);
        double best = -1.0;
        int bk = 0;
        for (int k = 0; k < 5; ++k) {
            double loss = KL[25 + k] / sqrt(KK[25 + k]);
            if (loss > best) { best = loss; bk = k; }
        }
        float lo, stp;
        sig_base(dsum, nzc, lo, stp);
        cc_sh = sig_c(lo, stp, wv + bk);
    }
    __syncthreads();
    const float cc = cc_sh;
    const float inv_n = 1.0f / (float)NN;

    int ti, tj;
    tri_decode(blockIdx.x, NBSW, ti, tj);
    const int r0 = ti * SB, c0 = tj * SB;
    const int tid = threadIdx.x;

#pragma unroll
    for (int q = 0; q < 4; ++q) {
        const int rr = q * 16 + (tid >> 4);
        const int cc4 = (tid & 15) * 4;
        float* p = d2 + (size_t)(r0 + rr) * NN + c0 + cc4;
        f32x4 v = *(const f32x4*)p;
        v[0] = fexp2(-v[0] * cc) * inv_n;
        v[1] = fexp2(-v[1] * cc) * inv_n;
        v[2] = fexp2(-v[2] * cc) * inv_n;
        v[3] = fexp2(-v[3] * cc) * inv_n;
        *(f32x4*)p = v;                              // direct (in-place)
        *(f32x4*)&st[rr][cc4] = v;                   // stage for mirror
    }

    if (ti != tj) {
        __syncthreads();
#pragma unroll
        for (int q = 0; q < 4; ++q) {
            const int tc = q * 16 + (tid >> 4);      // tile col = out row
            const int rb = (tid & 15) * 4;           // tile row base = out col base
            f32x4 vv = {st[rb + 0][tc], st[rb + 1][tc], st[rb + 2][tc], st[rb + 3][tc]};
            *(f32x4*)(d2 + (size_t)(c0 + tc) * NN + r0 + rb) = vv;
        }
    }
}

extern "C" void kernel_launch(void* const* d_in, const int* in_sizes, int n_in,
                              void* d_out, int out_size, void* d_ws, size_t ws_size,
                              hipStream_t stream) {
    const float* x  = (const float*)d_in[0];
    const float* lk = (const float*)d_in[1];
    float* out = (float*)d_out;   // d2 buffer + bf16 stash, transformed in place
    char* ws = (char*)d_ws;

    double* dsum = (double*)(ws + WS_DSUM);
    unsigned long long* nzc = (unsigned long long*)(ws + WS_NZC);
    double* KL = (double*)(ws + WS_KL);
    double* KK = (double*)(ws + WS_KK);
    float* sqv  = (float*)(ws + WS_SQ);

    hipLaunchKernelGGL(k_rowsq, dim3(NN / 256), dim3(256), 0, stream, x, sqv, dsum, nzc, KL, KK);
    hipLaunchKernelGGL(k_cvt, dim3(256), dim3(256), 0, stream, x, out);
    hipLaunchKernelGGL(k_d2, dim3(GRID_D2), dim3(512), 0, stream, x, sqv, out, dsum, nzc);
    hipLaunchKernelGGL(k_sweep_coarse, dim3(GRID_SW), dim3(256), 0, stream, out, lk, dsum, nzc, KL, KK);
    hipLaunchKernelGGL(k_sweep_refine, dim3(GRID_SW), dim3(256), 0, stream, out, lk, dsum, nzc, KL, KK);
    hipLaunchKernelGGL(k_final, dim3(NTILES), dim3(256), 0, stream, out, dsum, nzc, KL, KK);
}

// Round 25
// 141.210 us; speedup vs baseline: 1.0970x; 1.0469x over previous
//
#include <hip/hip_runtime.h>
#include <hip/hip_bf16.h>

#define NN 4096
#define DD 128
#define NS 75
#define TOT (NN * NN)

// k_d2: 128x128 tile, 512 threads / 8 waves (32x64 per wave), upper-tri grid
#define BT 128
#define NBD2 (NN / BT)                      // 32
#define GRID_D2 (NBD2 * (NBD2 + 1) / 2)     // 528

// sweeps/final: 64x64 tiles over upper triangle
#define SB 64
#define NBSW (NN / SB)                      // 64
#define NTILES (NBSW * (NBSW + 1) / 2)      // 2080
#define GRID_SW (NTILES / 2)                // 1040  (2 tiles/block in sweeps)

typedef float v2f __attribute__((ext_vector_type(2)));
typedef float f32x4 __attribute__((ext_vector_type(4)));
typedef short bf16x8 __attribute__((ext_vector_type(8)));

__device__ __forceinline__ float fexp2(float v) { return __builtin_amdgcn_exp2f(v); }

// async global->LDS, 16B per lane; lds dst is wave-uniform base (HW adds lane*16)
__device__ __forceinline__ void gload_lds16(const void* g, void* l) {
    __builtin_amdgcn_global_load_lds(
        (const __attribute__((address_space(1))) unsigned int*)g,
        (__attribute__((address_space(3))) unsigned int*)l,
        16, 0, 0);
}

// DPP lane-shift add: register-file crossing, no LDS latency.
template <int CTRL>
__device__ __forceinline__ float dpp_add(float x) {
    int y = __builtin_amdgcn_update_dpp(0, __float_as_int(x), CTRL, 0xf, 0xf, true);
    return x + __int_as_float(y);
}
__device__ __forceinline__ float wave_sum(float x) {   // result in lane 63
    x = dpp_add<0x111>(x);
    x = dpp_add<0x112>(x);
    x = dpp_add<0x114>(x);
    x = dpp_add<0x118>(x);
    x = dpp_add<0x142>(x);
    x = dpp_add<0x143>(x);
    return x;
}

// linear index -> (bi, bj) with bi <= bj, row-major over upper triangle
__device__ __forceinline__ void tri_decode(int t, int nb, int& bi, int& bj) {
    int b = 0, rem = t;
    while (rem >= nb - b) { rem -= nb - b; ++b; }
    bi = b; bj = b + rem;
}

// Split f32 -> bf16 hi + bf16 lo (exact residual truncated).
__device__ __forceinline__ void cvt_split(const float4& v0, const float4& v1,
                                          bf16x8& hi, bf16x8& lo) {
    float f[8] = {v0.x, v0.y, v0.z, v0.w, v1.x, v1.y, v1.z, v1.w};
#pragma unroll
    for (int j = 0; j < 8; ++j) {
        unsigned b = __float_as_uint(f[j]);
        hi[j] = (short)(b >> 16);
        float l = f[j] - __uint_as_float(b & 0xFFFF0000u);
        lo[j] = (short)(__float_as_uint(l) >> 16);
    }
}

// bf16 stash of x (hi/lo), hidden in d2's never-read lower triangle:
// x-row i (256B of bf16) lives at d2 row 2048+(i>>5) [+128 for lo],
// float-col (i&31)*64. All cols < 2048 <= row -> strictly lower-tri;
// sweeps read only upper tiles; k_final's mirror overwrites this at the
// very end (after all consumers). Written by k_cvt, read by k_d2.
__device__ __forceinline__ const unsigned short* xrow_st(const float* d2, int i, int lo) {
    return (const unsigned short*)(d2 + (size_t)(2048 + lo * 128 + (i >> 5)) * NN + (i & 31) * 64);
}
__device__ __forceinline__ unsigned short* xrow_st_w(float* d2, int i, int lo) {
    return (unsigned short*)(d2 + (size_t)(2048 + lo * 128 + (i >> 5)) * NN + (i & 31) * 64);
}

// Coarse window logic (deterministic; recomputed per consumer block).
__device__ __forceinline__ int coarse_window(const double* KL, const double* KK) {
    double best = -1.0;
    int bk = 0;
    for (int k = 0; k < 25; ++k) {
        double loss = KL[k] / sqrt(KK[k]);
        if (loss > best) { best = loss; bk = k; }   // strict > = first max
    }
    int wv = 3 * bk - 2;
    if (wv < 0) wv = 0;
    if (wv > NS - 5) wv = NS - 5;
    return wv;
}

// ---------------- ws layout (bytes) ----------------
#define WS_DSUM 0                      // double
#define WS_NZC  8                      // unsigned long long
#define WS_KL   16                     // double[32]  (0..24 coarse, 25..29 refine)
#define WS_KK   (16 + 256)             // double[32]
#define WS_SQ   (16 + 512)             // float[NN]
#define WS_CSIG (WS_SQ + 4 * NN)       // float[NS]

__global__ void k_rowsq(const float* __restrict__ x, float* __restrict__ sq,
                        double* __restrict__ dsum, unsigned long long* __restrict__ nzc) {
    int tid = blockIdx.x * blockDim.x + threadIdx.x;
    if (tid == 0) { *dsum = 0.0; *nzc = 0ull; }
    if (tid < NN) {
        const float4* row = (const float4*)(x + (size_t)tid * DD);
        float s = 0.f;
#pragma unroll
        for (int i = 0; i < DD / 4; ++i) {
            float4 v = row[i];
            s += v.x * v.x + v.y * v.y + v.z * v.z + v.w * v.w;
        }
        sq[tid] = s;
    }
}

// One-time x -> bf16 hi/lo decomposition (kills the 33x-redundant per-block
// cvt chains that latency-bound k_d2 through R19-R21).
__global__ void k_cvt(const float* __restrict__ x, float* __restrict__ d2) {
    int t = blockIdx.x * blockDim.x + threadIdx.x;
    int i  = t >> 4;
    int k8 = (t & 15) * 8;
    const float* p = x + (size_t)i * DD + k8;
    float4 v0 = *(const float4*)p;
    float4 v1 = *(const float4*)(p + 4);
    bf16x8 hi, lo;
    cvt_split(v0, v1, hi, lo);
    *(bf16x8*)(xrow_st_w(d2, i, 0) + k8) = hi;
    *(bf16x8*)(xrow_st_w(d2, i, 1) + k8) = lo;
}

// d2 via split-bf16 MFMA from the stash. 128x128 tile, 512 threads / 8 waves.
// Fragments loaded DIRECTLY as bf16 (1 dwordx4 per frag, zero cvt VALU).
// Writes UPPER TILE ONLY (k_final mirrors), staged coalesced via LDS.
__launch_bounds__(512, 2)
__global__ void k_d2(const float* __restrict__ x, const float* __restrict__ sq,
                     float* __restrict__ d2, double* __restrict__ dsum,
                     unsigned long long* __restrict__ nzc) {
    __shared__ float st[64][132];      // 33,792 B: 64-row staging pass, pad 4
    __shared__ double red_d[8];
    __shared__ int red_n[8];

    int bi, bj;
    tri_decode(blockIdx.x, NBD2, bi, bj);
    const int r0 = bi * BT, c0 = bj * BT;
    const int tid = threadIdx.x;
    const int l = tid & 63, wid = tid >> 6;
    const int wr = wid >> 1, wc = wid & 1;
    const int lr = l & 15;
    const int lk = (l >> 4) * 8;
    const int l4 = (l >> 4) * 4;

    const int arow = r0 + wr * 32 + lr;     // + a*16
    const int brow = c0 + wc * 64 + lr;     // + b*16

    f32x4 acc[2][4];
#pragma unroll
    for (int a = 0; a < 2; ++a)
#pragma unroll
        for (int b = 0; b < 4; ++b) acc[a][b] = (f32x4){0.f, 0.f, 0.f, 0.f};

#pragma unroll
    for (int kc = 0; kc < 4; ++kc) {
        const int k0 = kc * 32 + lk;
        bf16x8 ah[2], al[2], bh[4], bl[4];
#pragma unroll
        for (int a = 0; a < 2; ++a) {
            ah[a] = *(const bf16x8*)(xrow_st(d2, arow + a * 16, 0) + k0);
            al[a] = *(const bf16x8*)(xrow_st(d2, arow + a * 16, 1) + k0);
        }
#pragma unroll
        for (int b = 0; b < 4; ++b) {
            bh[b] = *(const bf16x8*)(xrow_st(d2, brow + b * 16, 0) + k0);
            bl[b] = *(const bf16x8*)(xrow_st(d2, brow + b * 16, 1) + k0);
        }
#pragma unroll
        for (int a = 0; a < 2; ++a)
#pragma unroll
            for (int b = 0; b < 4; ++b) {
                acc[a][b] = __builtin_amdgcn_mfma_f32_16x16x32_bf16(ah[a], bh[b], acc[a][b], 0, 0, 0);
                acc[a][b] = __builtin_amdgcn_mfma_f32_16x16x32_bf16(ah[a], bl[b], acc[a][b], 0, 0, 0);
                acc[a][b] = __builtin_amdgcn_mfma_f32_16x16x32_bf16(al[a], bh[b], acc[a][b], 0, 0, 0);
            }
    }

    // d2 = max(sq_r + sq_c - 2G, 0); dist-sum/nnz reduction.
    float myd = 0.f;
    int myn = 0;
#pragma unroll
    for (int a = 0; a < 2; ++a) {
        const int grb = r0 + wr * 32 + a * 16 + l4;
        float4 sqr = *(const float4*)(sq + grb);
        float sr[4] = {sqr.x, sqr.y, sqr.z, sqr.w};
#pragma unroll
        for (int b = 0; b < 4; ++b) {
            const float sc = sq[c0 + wc * 64 + b * 16 + lr];
#pragma unroll
            for (int v = 0; v < 4; ++v) {
                float d = fmaxf(sr[v] + sc - 2.f * acc[a][b][v], 0.f);
                acc[a][b][v] = d;
                if (d > 0.f) { myd += sqrtf(d); ++myn; }
            }
        }
    }
    const int w = (bi == bj) ? 1 : 2;
    float sd = wave_sum(myd);
    float sn = wave_sum((float)myn);
    if (l == 63) { red_d[wid] = (double)sd; red_n[wid] = (int)sn; }

    // Two 64-row staging passes; waves wr in {2p, 2p+1} stage, all write.
#pragma unroll
    for (int p = 0; p < 2; ++p) {
        __syncthreads();
        if ((wr >> 1) == p) {
            const int lrow = (wr & 1) * 32 + l4;    // 0..63 within pass
#pragma unroll
            for (int a = 0; a < 2; ++a)
#pragma unroll
                for (int b = 0; b < 4; ++b)
#pragma unroll
                    for (int v = 0; v < 4; ++v)
                        st[lrow + (a == 1 ? 16 : 0) + v][wc * 64 + b * 16 + lr] = acc[a][b][v];
        }
        __syncthreads();
        // cooperative coalesced write: 64 rows x 128 cols, 512B runs
#pragma unroll
        for (int q = 0; q < 4; ++q) {
            const int rr = q * 16 + (tid >> 5);     // 0..63
            const int cc = (tid & 31) * 4;          // 0..124
            *(f32x4*)(d2 + (size_t)(r0 + p * 64 + rr) * NN + c0 + cc) =
                *(const f32x4*)&st[rr][cc];
        }
    }

    if (tid == 0) {
        double td = 0.0;
        int tn = 0;
#pragma unroll
        for (int q = 0; q < 8; ++q) { td += red_d[q]; tn += red_n[q]; }
        atomicAdd(dsum, td * (double)w);
        atomicAdd(nzc, (unsigned long long)(tn * w));
    }
}

__global__ void k_sigmas(const double* __restrict__ dsum, const unsigned long long* __restrict__ nzc,
                         float* __restrict__ csig, double* __restrict__ KL, double* __restrict__ KK) {
    int t = threadIdx.x;
    float mean = (float)(*dsum / (double)(*nzc));
    float lo = 0.1f * mean;
    float hi = 10.0f * mean;
    float step = (hi - lo) / (float)NS;
    if (t < NS) {
        float s = lo + step * (float)t;
        csig[t] = (float)(1.4426950408889634 / ((double)s * (double)s));
    }
    if (t < 32) { KL[t] = 0.0; KK[t] = 0.0; }
}

// One sigma-phase over register-resident data. ADD=false stores w*v,
// ADD=true accumulates (second tile).
template <bool ADD, int CH, int S0, int STRIDE, int NSLOT>
__device__ __forceinline__ void sweep_phase(const v2f* nd, const v2f* ll,
                                            const float* __restrict__ csig, int off,
                                            double part[4][2 * NSLOT],
                                            int wave, int lane, float w) {
    float c[CH];
#pragma unroll
    for (int s = 0; s < CH; ++s)   // force SGPR residency
        c[s] = __int_as_float(__builtin_amdgcn_readfirstlane(
                   __float_as_int(csig[off + STRIDE * (S0 + s)])));
    v2f akl[CH], akk[CH];
#pragma unroll
    for (int s = 0; s < CH; ++s) { akl[s] = (v2f){0.f, 0.f}; akk[s] = (v2f){0.f, 0.f}; }

#pragma unroll
    for (int e = 0; e < 8; ++e) {
        v2f ndv = nd[e], L = ll[e];
#pragma unroll
        for (int s = 0; s < CH; ++s) {
            v2f arg = ndv * c[s];                               // v_pk_mul_f32
            v2f K = {fexp2(arg.x), fexp2(arg.y)};               // 2x v_exp_f32
            akl[s] = __builtin_elementwise_fma(K, L, akl[s]);   // v_pk_fma_f32
            akk[s] = __builtin_elementwise_fma(K, K, akk[s]);
        }
    }

#pragma unroll
    for (int s = 0; s < CH; ++s) {
        float v1 = wave_sum(akl[s].x + akl[s].y);
        float v2 = wave_sum(akk[s].x + akk[s].y);
        if (lane == 63) {
            if (ADD) {
                part[wave][S0 + s]         += (double)(v1 * w);
                part[wave][NSLOT + S0 + s] += (double)(v2 * w);
            } else {
                part[wave][S0 + s]         = (double)(v1 * w);
                part[wave][NSLOT + S0 + s] = (double)(v2 * w);
            }
        }
    }
}

// Direct (tile0) load: 16 elems/thread into registers.
__device__ __forceinline__ void sweep_load_direct(const float* __restrict__ d2,
                                                  const float* __restrict__ lk,
                                                  int r0, int c0, v2f* nd, v2f* ll) {
    const int rr = threadIdx.x >> 4;
    const int c4 = (threadIdx.x & 15) * 4;
#pragma unroll
    for (int it = 0; it < 4; ++it) {
        size_t off = (size_t)(r0 + rr + 16 * it) * NN + c0 + c4;
        float4 dv = *(const float4*)(d2 + off);
        float4 lv = *(const float4*)(lk + off);
        nd[it * 2 + 0] = (v2f){-dv.x, -dv.y};
        nd[it * 2 + 1] = (v2f){-dv.z, -dv.w};
        ll[it * 2 + 0] = (v2f){lv.x, lv.y};
        ll[it * 2 + 1] = (v2f){lv.z, lv.w};
    }
}

// Prefetch (tile1) via global_load_lds into this wave's 8KB LDS slot.
__device__ __forceinline__ void sweep_prefetch(const float* __restrict__ d2,
                                               const float* __restrict__ lk,
                                               int r0, int c0, char* wbuf) {
    const int l = threadIdx.x & 63;
    const int wave4 = (threadIdx.x >> 6) * 4;
    const int rr = wave4 + (l >> 4);
    const int c4 = (l & 15) * 4;
#pragma unroll
    for (int q = 0; q < 4; ++q) {
        size_t off = (size_t)(r0 + rr + 16 * q) * NN + c0 + c4;
        gload_lds16(d2 + off, wbuf + q * 1024);
        gload_lds16(lk + off, wbuf + (4 + q) * 1024);
    }
}

__device__ __forceinline__ void sweep_unpack(const char* wbuf, v2f* nd, v2f* ll) {
    const int l = threadIdx.x & 63;
#pragma unroll
    for (int q = 0; q < 4; ++q) {
        f32x4 dv = *(const f32x4*)(wbuf + q * 1024 + l * 16);
        f32x4 lv = *(const f32x4*)(wbuf + (4 + q) * 1024 + l * 16);
        nd[q * 2 + 0] = (v2f){-dv[0], -dv[1]};
        nd[q * 2 + 1] = (v2f){-dv[2], -dv[3]};
        ll[q * 2 + 0] = (v2f){lv[0], lv[1]};
        ll[q * 2 + 1] = (v2f){lv[2], lv[3]};
    }
}

// Coarse: 2 tiles/block; tile1 async-prefetched under tile0's 25-sigma compute.
__launch_bounds__(256, 3)
__global__ void k_sweep_coarse(const float* __restrict__ d2, const float* __restrict__ lk,
                               const float* __restrict__ csig, double* __restrict__ KL,
                               double* __restrict__ KK) {
    __shared__ char pbuf[4][8192];
    __shared__ double part[4][50];
    const int lane = threadIdx.x & 63, wave = threadIdx.x >> 6;

    int t0 = blockIdx.x * 2, t1 = t0 + 1;
    int bi0, bj0, bi1, bj1;
    tri_decode(t0, NBSW, bi0, bj0);
    tri_decode(t1, NBSW, bi1, bj1);
    const float w0 = (bi0 == bj0) ? 1.f : 2.f;
    const float w1 = (bi1 == bj1) ? 1.f : 2.f;

    sweep_prefetch(d2, lk, bi1 * SB, bj1 * SB, &pbuf[wave][0]);
    v2f nd[8], ll[8];
    sweep_load_direct(d2, lk, bi0 * SB, bj0 * SB, nd, ll);

    sweep_phase<false, 13, 0, 3, 25>(nd, ll, csig, 0, part, wave, lane, w0);
    sweep_phase<false, 12, 13, 3, 25>(nd, ll, csig, 0, part, wave, lane, w0);

    asm volatile("s_waitcnt vmcnt(0)" ::: "memory");
    sweep_unpack(&pbuf[wave][0], nd, ll);

    sweep_phase<true, 13, 0, 3, 25>(nd, ll, csig, 0, part, wave, lane, w1);
    sweep_phase<true, 12, 13, 3, 25>(nd, ll, csig, 0, part, wave, lane, w1);

    __syncthreads();
    const int t = threadIdx.x;
    if (t < 50) {
        double v = part[0][t] + part[1][t] + part[2][t] + part[3][t];
        if (t < 25) atomicAdd(&KL[t], v);
        else        atomicAdd(&KK[t - 25], v);
    }
}

// Refine: same 2-tile structure, 5 stride-1 sigmas at the coarse window.
__launch_bounds__(256, 3)
__global__ void k_sweep_refine(const float* __restrict__ d2, const float* __restrict__ lk,
                               const float* __restrict__ csig, double* __restrict__ KL,
                               double* __restrict__ KK) {
    __shared__ char pbuf[4][8192];
    __shared__ double part[4][10];
    __shared__ int w0_sh;
    if (threadIdx.x == 0) w0_sh = coarse_window(KL, KK);
    const int lane = threadIdx.x & 63, wave = threadIdx.x >> 6;

    int t0 = blockIdx.x * 2, t1 = t0 + 1;
    int bi0, bj0, bi1, bj1;
    tri_decode(t0, NBSW, bi0, bj0);
    tri_decode(t1, NBSW, bi1, bj1);
    const float wt0 = (bi0 == bj0) ? 1.f : 2.f;
    const float wt1 = (bi1 == bj1) ? 1.f : 2.f;

    sweep_prefetch(d2, lk, bi1 * SB, bj1 * SB, &pbuf[wave][0]);
    v2f nd[8], ll[8];
    sweep_load_direct(d2, lk, bi0 * SB, bj0 * SB, nd, ll);
    __syncthreads();                 // w0_sh visible
    const int s0 = w0_sh;

    sweep_phase<false, 5, 0, 1, 5>(nd, ll, csig, s0, part, wave, lane, wt0);

    asm volatile("s_waitcnt vmcnt(0)" ::: "memory");
    sweep_unpack(&pbuf[wave][0], nd, ll);

    sweep_phase<true, 5, 0, 1, 5>(nd, ll, csig, s0, part, wave, lane, wt1);

    __syncthreads();
    const int t = threadIdx.x;
    if (t < 10) {
        double v = part[0][t] + part[1][t] + part[2][t] + part[3][t];
        if (t < 5) atomicAdd(&KL[25 + t], v);
        else       atomicAdd(&KK[25 + t - 5], v);
    }
}

// Final: tile-based over the upper triangle (grid 2080). Reads the upper
// d2 tile, A = exp2(-d2*c)/n, direct write + LDS-transposed mirror
// (also overwrites the bf16 stash — last consumer, safe).
__global__ void k_final(float* __restrict__ d2, const double* __restrict__ KL,
                        const double* __restrict__ KK, const float* __restrict__ csig) {
    __shared__ float st[64][68];
    __shared__ float cc_sh;
    if (threadIdx.x == 0) {
        int wv = coarse_window(KL, KK);
        double best = -1.0;
        int bk = 0;
        for (int k = 0; k < 5; ++k) {
            double loss = KL[25 + k] / sqrt(KK[25 + k]);
            if (loss > best) { best = loss; bk = k; }
        }
        cc_sh = csig[wv + bk];
    }
    __syncthreads();
    const float cc = cc_sh;
    const float inv_n = 1.0f / (float)NN;

    int ti, tj;
    tri_decode(blockIdx.x, NBSW, ti, tj);
    const int r0 = ti * SB, c0 = tj * SB;
    const int tid = threadIdx.x;

#pragma unroll
    for (int q = 0; q < 4; ++q) {
        const int rr = q * 16 + (tid >> 4);
        const int cc4 = (tid & 15) * 4;
        float* p = d2 + (size_t)(r0 + rr) * NN + c0 + cc4;
        f32x4 v = *(const f32x4*)p;
        v[0] = fexp2(-v[0] * cc) * inv_n;
        v[1] = fexp2(-v[1] * cc) * inv_n;
        v[2] = fexp2(-v[2] * cc) * inv_n;
        v[3] = fexp2(-v[3] * cc) * inv_n;
        *(f32x4*)p = v;                              // direct (in-place)
        *(f32x4*)&st[rr][cc4] = v;                   // stage for mirror
    }

    if (ti != tj) {
        __syncthreads();
#pragma unroll
        for (int q = 0; q < 4; ++q) {
            const int tc = q * 16 + (tid >> 4);      // tile col = out row
            const int rb = (tid & 15) * 4;           // tile row base = out col base
            f32x4 vv = {st[rb + 0][tc], st[rb + 1][tc], st[rb + 2][tc], st[rb + 3][tc]};
            *(f32x4*)(d2 + (size_t)(c0 + tc) * NN + r0 + rb) = vv;
        }
    }
}

extern "C" void kernel_launch(void* const* d_in, const int* in_sizes, int n_in,
                              void* d_out, int out_size, void* d_ws, size_t ws_size,
                              hipStream_t stream) {
    const float* x  = (const float*)d_in[0];
    const float* lk = (const float*)d_in[1];
    float* out = (float*)d_out;   // d2 buffer + bf16 stash, transformed in place
    char* ws = (char*)d_ws;

    double* dsum = (double*)(ws + WS_DSUM);
    unsigned long long* nzc = (unsigned long long*)(ws + WS_NZC);
    double* KL = (double*)(ws + WS_KL);
    double* KK = (double*)(ws + WS_KK);
    float* sqv  = (float*)(ws + WS_SQ);
    float* csig = (float*)(ws + WS_CSIG);

    hipLaunchKernelGGL(k_rowsq, dim3(NN / 256), dim3(256), 0, stream, x, sqv, dsum, nzc);
    hipLaunchKernelGGL(k_cvt, dim3(256), dim3(256), 0, stream, x, out);
    hipLaunchKernelGGL(k_d2, dim3(GRID_D2), dim3(512), 0, stream, x, sqv, out, dsum, nzc);
    hipLaunchKernelGGL(k_sigmas, dim3(1), dim3(128), 0, stream, dsum, nzc, csig, KL, KK);
    hipLaunchKernelGGL(k_sweep_coarse, dim3(GRID_SW), dim3(256), 0, stream, out, lk, csig, KL, KK);
    hipLaunchKernelGGL(k_sweep_refine, dim3(GRID_SW), dim3(256), 0, stream, out, lk, csig, KL, KK);
    hipLaunchKernelGGL(k_final, dim3(NTILES), dim3(256), 0, stream, out, KL, KK, csig);
}